// Round 2
// baseline (327.366 us; speedup 1.0000x reference)
//
#include <hip/hip_runtime.h>

#define HD 1024
#define FD 2816
#define NE 8
#define NT 1024

typedef short short8 __attribute__((ext_vector_type(8)));
typedef short short4v __attribute__((ext_vector_type(4)));
typedef float f32x4 __attribute__((ext_vector_type(4)));

typedef __attribute__((address_space(3))) unsigned lds_u32;
typedef __attribute__((address_space(1))) const unsigned glb_u32;

__device__ __forceinline__ void glds16(const void* g, void* l) {
  __builtin_amdgcn_global_load_lds((glb_u32*)g, (lds_u32*)l, 16, 0, 0);
}

__device__ __forceinline__ short f2bf(float f) {
  unsigned u = __builtin_bit_cast(unsigned, f);
  u += 0x7FFFu + ((u >> 16) & 1u);   // round-to-nearest-even
  return (short)(u >> 16);
}
__device__ __forceinline__ int imin(int a, int b) { return a < b ? a : b; }

// ---------------- router ----------------------------------------------------
__global__ void router_kernel(const float* __restrict__ x,
                              const float* __restrict__ rw,
                              int* __restrict__ counts,
                              int* __restrict__ tok_i,
                              float* __restrict__ tok_w) {
  const int t = blockIdx.x;
  const int lane = threadIdx.x;
  const float* px = x + (size_t)t * HD;
  float acc[NE];
#pragma unroll
  for (int e = 0; e < NE; e++) acc[e] = 0.f;
  for (int h = lane; h < HD; h += 64) {
    float xv = px[h];
#pragma unroll
    for (int e = 0; e < NE; e++) acc[e] += xv * rw[e * HD + h];
  }
#pragma unroll
  for (int e = 0; e < NE; e++) {
#pragma unroll
    for (int off = 32; off > 0; off >>= 1)
      acc[e] += __shfl_xor(acc[e], off, 64);
  }
  if (lane == 0) {
    float mx = acc[0];
#pragma unroll
    for (int e = 1; e < NE; e++) mx = fmaxf(mx, acc[e]);
    float ex[NE];
#pragma unroll
    for (int e = 0; e < NE; e++) ex[e] = __expf(acc[e] - mx);
    int i1 = 0;
#pragma unroll
    for (int e = 1; e < NE; e++) if (ex[e] > ex[i1]) i1 = e;
    int i2 = (i1 == 0) ? 1 : 0;
#pragma unroll
    for (int e = 0; e < NE; e++) if (e != i1 && ex[e] > ex[i2]) i2 = e;
    float inv = 1.f / (ex[i1] + ex[i2]);
    tok_i[t * 2 + 0] = i1; tok_w[t * 2 + 0] = ex[i1] * inv;
    tok_i[t * 2 + 1] = i2; tok_w[t * 2 + 1] = ex[i2] * inv;
    atomicAdd(&counts[i1], 1);
    atomicAdd(&counts[i2], 1);
  }
}

// ---------------- scan ------------------------------------------------------
__global__ void scan_kernel(const int* __restrict__ counts,
                            int* __restrict__ bases,
                            int* __restrict__ cursor) {
  if (threadIdx.x == 0) {
    int s = 0;
    for (int e = 0; e < NE; e++) { bases[e] = s; cursor[e] = s; s += counts[e]; }
    bases[NE] = s;
  }
}

// ---------------- fill ------------------------------------------------------
__global__ void fill_kernel(const int* __restrict__ tok_i,
                            const float* __restrict__ tok_w,
                            int* __restrict__ cursor,
                            int* __restrict__ slot_token,
                            float* __restrict__ slot_w,
                            int* __restrict__ slot_of) {
  int t = blockIdx.x * 256 + threadIdx.x;
  if (t >= NT) return;
#pragma unroll
  for (int k = 0; k < 2; k++) {
    int e = tok_i[t * 2 + k];
    int pos = atomicAdd(&cursor[e], 1);
    slot_token[pos] = t;
    slot_w[pos] = tok_w[t * 2 + k];
    slot_of[t * 2 + k] = pos;
  }
}

// ---------------- gate+up grouped GEMM (BM=64 BN=64 BK=64, pipelined) -------
// grid: (FD/64, 16, NE), block 256
__global__ __launch_bounds__(256) void gateup_kernel(
    const float* __restrict__ x, const float* __restrict__ gate_w,
    const float* __restrict__ up_w, const int* __restrict__ bases,
    const int* __restrict__ slot_token, short* __restrict__ m_out) {
  const int e = blockIdx.z;
  const int b0 = bases[e];
  const int ne = bases[e + 1] - b0;
  const int row0 = blockIdx.y * 64;
  if (row0 >= ne) return;
  const int n0 = blockIdx.x * 64;

  __shared__ short As[2][64 * 72];
  __shared__ short Gs[2][64 * 72];
  __shared__ short Us[2][64 * 72];

  const int tid = threadIdx.x;
  const int lane = tid & 63, wid = tid >> 6;

  // A staging: one row, 16 k per thread
  const int ar = tid >> 2, aq = tid & 3;
  const int tokA = slot_token[b0 + imin(row0 + ar, ne - 1)];
  const float* pxa = x + (size_t)tokA * HD + aq * 16;

  // B staging: mat per wave-pair; kq fast (16), fq in {fh, fh+8}
  const int mat = tid >> 7;
  const int rem = tid & 127;
  const int bkq = rem & 15, fh = rem >> 4;
  const float* wsel = (mat ? up_w : gate_w) + (size_t)e * HD * FD + n0;

  const int wm = wid >> 1, wn = wid & 1;
  const int l15 = lane & 15, l4 = lane >> 4;

  f32x4 accG[2][2], accU[2][2];
#pragma unroll
  for (int mi = 0; mi < 2; mi++)
#pragma unroll
    for (int ni = 0; ni < 2; ni++) { accG[mi][ni] = (f32x4)0.f; accU[mi][ni] = (f32x4)0.f; }

  f32x4 av[4], bv0[4], bv1[4];

  auto loadA = [&](int k0) {
#pragma unroll
    for (int j = 0; j < 4; j++) av[j] = *(const f32x4*)(pxa + k0 + j * 4);
  };
  auto writeA = [&](int buf) {
    short8 s0, s1;
#pragma unroll
    for (int j = 0; j < 8; j++) {
      s0[j] = f2bf(av[j >> 2][j & 3]);
      s1[j] = f2bf(av[2 + (j >> 2)][j & 3]);
    }
    *(short8*)&As[buf][ar * 72 + aq * 16] = s0;
    *(short8*)&As[buf][ar * 72 + aq * 16 + 8] = s1;
  };
  auto loadB = [&](int k0) {
#pragma unroll
    for (int kk = 0; kk < 4; kk++) {
      const float* p = wsel + (size_t)(k0 + bkq * 4 + kk) * FD;
      bv0[kk] = *(const f32x4*)(p + fh * 4);
      bv1[kk] = *(const f32x4*)(p + (fh + 8) * 4);
    }
  };
  auto writeB = [&](int buf) {
    short* Bd = mat ? Us[buf] : Gs[buf];
#pragma unroll
    for (int ff = 0; ff < 4; ff++) {
      short4v w0, w1;
#pragma unroll
      for (int kk = 0; kk < 4; kk++) { w0[kk] = f2bf(bv0[kk][ff]); w1[kk] = f2bf(bv1[kk][ff]); }
      *(short4v*)&Bd[(fh * 4 + ff) * 72 + bkq * 4] = w0;
      *(short4v*)&Bd[((fh + 8) * 4 + ff) * 72 + bkq * 4] = w1;
    }
  };

  const int NTL = HD / 64;   // 16
  loadA(0); loadB(0); writeA(0); writeB(0);
  loadA(64); loadB(64);
  __syncthreads();

  for (int t = 0; t < NTL; t++) {
    const int cur = t & 1;
#pragma unroll
    for (int kk = 0; kk < 2; kk++) {
      short8 afr[2], bgf[2], buf_[2];
#pragma unroll
      for (int mi = 0; mi < 2; mi++) {
        int R = wm * 32 + mi * 16 + l15;
        afr[mi] = *(const short8*)&As[cur][R * 72 + kk * 32 + l4 * 8];
      }
#pragma unroll
      for (int ni = 0; ni < 2; ni++) {
        int N = wn * 32 + ni * 16 + l15;
        bgf[ni] = *(const short8*)&Gs[cur][N * 72 + kk * 32 + l4 * 8];
        buf_[ni] = *(const short8*)&Us[cur][N * 72 + kk * 32 + l4 * 8];
      }
#pragma unroll
      for (int mi = 0; mi < 2; mi++)
#pragma unroll
        for (int ni = 0; ni < 2; ni++) {
          accG[mi][ni] = __builtin_amdgcn_mfma_f32_16x16x32_bf16(afr[mi], bgf[ni], accG[mi][ni], 0, 0, 0);
          accU[mi][ni] = __builtin_amdgcn_mfma_f32_16x16x32_bf16(afr[mi], buf_[ni], accU[mi][ni], 0, 0, 0);
        }
    }
    if (t + 1 < NTL) { writeA(cur ^ 1); writeB(cur ^ 1); }
    __syncthreads();
    if (t + 2 < NTL) { loadA((t + 2) * 64); loadB((t + 2) * 64); }
  }

#pragma unroll
  for (int mi = 0; mi < 2; mi++)
#pragma unroll
    for (int ni = 0; ni < 2; ni++)
#pragma unroll
      for (int r = 0; r < 4; r++) {
        int row = row0 + wm * 32 + mi * 16 + l4 * 4 + r;
        if (row < ne) {
          float g = accG[mi][ni][r];
          float u = accU[mi][ni][r];
          float mv = (g / (1.f + __expf(-g))) * u;
          int f = n0 + wn * 32 + ni * 16 + l15;
          m_out[(size_t)(b0 + row) * FD + f] = f2bf(mv);
        }
      }
}

// ---------------- down grouped GEMM (BM=64 BN=64 BK=64, glds A, pipelined) --
// grid: (HD/64, 16, NE), block 256
__global__ __launch_bounds__(256) void down_kernel(
    const short* __restrict__ m_in, const float* __restrict__ down_w,
    const int* __restrict__ bases, const float* __restrict__ slot_w,
    float* __restrict__ out_slot) {
  const int e = blockIdx.z;
  const int b0 = bases[e];
  const int ne = bases[e + 1] - b0;
  const int row0 = blockIdx.y * 64;
  if (row0 >= ne) return;
  const int n0 = blockIdx.x * 64;

  __shared__ short As[2][64 * 64];   // linear dest, src-swizzled (oct ^= row&7)
  __shared__ short Bs[2][64 * 72];

  const int tid = threadIdx.x;
  const int lane = tid & 63, wid = tid >> 6;

  // A via global_load_lds: chunk i (16B) -> LDS i*16; row=i>>3; src oct=(i&7)^(row&7)
  const int i1 = tid, i2 = tid + 256;
  const int r1 = i1 >> 3, r2 = i2 >> 3;
  const int s1 = b0 + imin(row0 + r1, ne - 1);
  const int s2 = b0 + imin(row0 + r2, ne - 1);
  const short* pa1 = m_in + (size_t)s1 * FD + ((i1 & 7) ^ (r1 & 7)) * 8;
  const short* pa2 = m_in + (size_t)s2 * FD + ((i2 & 7) ^ (r2 & 7)) * 8;

  const int bkq = tid & 15, fq = tid >> 4;
  const float* wb = down_w + (size_t)e * FD * HD + n0 + fq * 4;

  const int wm = wid >> 1, wn = wid & 1;
  const int l15 = lane & 15, l4 = lane >> 4;

  f32x4 acc[2][2];
#pragma unroll
  for (int mi = 0; mi < 2; mi++)
#pragma unroll
    for (int ni = 0; ni < 2; ni++) acc[mi][ni] = (f32x4)0.f;

  f32x4 bv[4];

  auto stageA = [&](int buf, int k0) {
    glds16(pa1 + k0, &As[buf][wid * 512]);
    glds16(pa2 + k0, &As[buf][2048 + wid * 512]);
  };
  auto loadB = [&](int k0) {
#pragma unroll
    for (int kk = 0; kk < 4; kk++)
      bv[kk] = *(const f32x4*)(wb + (size_t)(k0 + bkq * 4 + kk) * HD);
  };
  auto writeB = [&](int buf) {
#pragma unroll
    for (int ff = 0; ff < 4; ff++) {
      short4v wv;
#pragma unroll
      for (int kk = 0; kk < 4; kk++) wv[kk] = f2bf(bv[kk][ff]);
      *(short4v*)&Bs[buf][(fq * 4 + ff) * 72 + bkq * 4] = wv;
    }
  };

  const int NTL = FD / 64;   // 44
  stageA(0, 0); loadB(0); writeB(0);
  stageA(1, 64); loadB(64);
  __syncthreads();

  for (int t = 0; t < NTL; t++) {
    const int cur = t & 1;
    const char* Ab = (const char*)As[cur];
    const char* Bb = (const char*)Bs[cur];
#pragma unroll
    for (int kk = 0; kk < 2; kk++) {
      short8 afr[2], bfr[2];
#pragma unroll
      for (int mi = 0; mi < 2; mi++) {
        int R = wm * 32 + mi * 16 + l15;
        int cb = (kk * 64 + l4 * 16) ^ ((R & 7) << 4);
        afr[mi] = *(const short8*)(Ab + R * 128 + cb);
      }
#pragma unroll
      for (int ni = 0; ni < 2; ni++) {
        int N = wn * 32 + ni * 16 + l15;
        bfr[ni] = *(const short8*)(Bb + N * 144 + kk * 64 + l4 * 16);
      }
#pragma unroll
      for (int mi = 0; mi < 2; mi++)
#pragma unroll
        for (int ni = 0; ni < 2; ni++)
          acc[mi][ni] = __builtin_amdgcn_mfma_f32_16x16x32_bf16(afr[mi], bfr[ni], acc[mi][ni], 0, 0, 0);
    }
    if (t + 1 < NTL) writeB(cur ^ 1);
    __syncthreads();
    if (t + 2 < NTL) { stageA(cur, (t + 2) * 64); loadB((t + 2) * 64); }
  }

#pragma unroll
  for (int mi = 0; mi < 2; mi++)
#pragma unroll
    for (int ni = 0; ni < 2; ni++)
#pragma unroll
      for (int r = 0; r < 4; r++) {
        int row = row0 + wm * 32 + mi * 16 + l4 * 4 + r;
        if (row < ne) {
          int slot = b0 + row;
          out_slot[(size_t)slot * HD + n0 + wn * 32 + ni * 16 + l15] =
              acc[mi][ni][r] * slot_w[slot];
        }
      }
}

// ---------------- combine ---------------------------------------------------
__global__ void combine_kernel(const float* __restrict__ out_slot,
                               const int* __restrict__ slot_of,
                               float* __restrict__ out) {
  const int t = blockIdx.x;
  const int s0 = slot_of[t * 2];
  const int s1 = slot_of[t * 2 + 1];
  const int i = threadIdx.x * 4;
  f32x4 a = *(const f32x4*)(out_slot + (size_t)s0 * HD + i);
  f32x4 b = *(const f32x4*)(out_slot + (size_t)s1 * HD + i);
  f32x4 c = a + b;
  *(f32x4*)(out + (size_t)t * HD + i) = c;
}

extern "C" void kernel_launch(void* const* d_in, const int* in_sizes, int n_in,
                              void* d_out, int out_size, void* d_ws,
                              size_t ws_size, hipStream_t stream) {
  const float* x = (const float*)d_in[0];
  const float* rw = (const float*)d_in[1];
  const float* gw = (const float*)d_in[2];
  const float* uw = (const float*)d_in[3];
  const float* dw = (const float*)d_in[4];
  float* out = (float*)d_out;

  char* ws = (char*)d_ws;
  int* counts = (int*)(ws + 0);
  int* cursor = (int*)(ws + 64);
  int* bases = (int*)(ws + 128);
  int* tok_i = (int*)(ws + 256);
  float* tok_w = (float*)(ws + 256 + 8192);
  int* slot_token = (int*)(ws + 256 + 16384);
  float* slot_w = (float*)(ws + 256 + 24576);
  int* slot_of = (int*)(ws + 256 + 32768);
  short* m_buf = (short*)(ws + 41216);                 // 2048 x 2816 bf16
  float* out_slot = (float*)(ws + 41216 + 11534336);   // 2048 x 1024 f32

  hipMemsetAsync(counts, 0, 64, stream);
  router_kernel<<<NT, 64, 0, stream>>>(x, rw, counts, tok_i, tok_w);
  scan_kernel<<<1, 64, 0, stream>>>(counts, bases, cursor);
  fill_kernel<<<NT / 256, 256, 0, stream>>>(tok_i, tok_w, cursor, slot_token,
                                            slot_w, slot_of);
  gateup_kernel<<<dim3(FD / 64, 16, NE), 256, 0, stream>>>(
      x, gw, uw, bases, slot_token, m_buf);
  down_kernel<<<dim3(HD / 64, 16, NE), 256, 0, stream>>>(
      m_buf, dw, bases, slot_w, out_slot);
  combine_kernel<<<NT, 256, 0, stream>>>(out_slot, slot_of, out);
}

// Round 3
// 211.681 us; speedup vs baseline: 1.5465x; 1.5465x over previous
//
#include <hip/hip_runtime.h>

#define HD 1024
#define FD 2816
#define NE 8
#define NT 1024
#define NSLOT (NT * 2)
#define BMG 320   // m-tile: >= max plausible tokens/expert -> weights read once

typedef short short8 __attribute__((ext_vector_type(8)));
typedef short short4v __attribute__((ext_vector_type(4)));
typedef float f32x4 __attribute__((ext_vector_type(4)));

typedef __attribute__((address_space(3))) unsigned lds_u32;
typedef __attribute__((address_space(1))) const unsigned glb_u32;

__device__ __forceinline__ void glds16(const void* g, void* l) {
  __builtin_amdgcn_global_load_lds((glb_u32*)g, (lds_u32*)l, 16, 0, 0);
}

__device__ __forceinline__ short f2bf(float f) {
  unsigned u = __builtin_bit_cast(unsigned, f);
  u += 0x7FFFu + ((u >> 16) & 1u);   // round-to-nearest-even
  return (short)(u >> 16);
}
__device__ __forceinline__ int imin(int a, int b) { return a < b ? a : b; }

// ---------------- router ----------------------------------------------------
__global__ void router_kernel(const float* __restrict__ x,
                              const float* __restrict__ rw,
                              int* __restrict__ counts,
                              int* __restrict__ tok_i,
                              float* __restrict__ tok_w) {
  const int t = blockIdx.x;
  const int lane = threadIdx.x;
  const float* px = x + (size_t)t * HD;
  float acc[NE];
#pragma unroll
  for (int e = 0; e < NE; e++) acc[e] = 0.f;
  for (int h = lane; h < HD; h += 64) {
    float xv = px[h];
#pragma unroll
    for (int e = 0; e < NE; e++) acc[e] += xv * rw[e * HD + h];
  }
#pragma unroll
  for (int e = 0; e < NE; e++) {
#pragma unroll
    for (int off = 32; off > 0; off >>= 1)
      acc[e] += __shfl_xor(acc[e], off, 64);
  }
  if (lane == 0) {
    float mx = acc[0];
#pragma unroll
    for (int e = 1; e < NE; e++) mx = fmaxf(mx, acc[e]);
    float ex[NE];
#pragma unroll
    for (int e = 0; e < NE; e++) ex[e] = __expf(acc[e] - mx);
    int i1 = 0;
#pragma unroll
    for (int e = 1; e < NE; e++) if (ex[e] > ex[i1]) i1 = e;
    int i2 = (i1 == 0) ? 1 : 0;
#pragma unroll
    for (int e = 0; e < NE; e++) if (e != i1 && ex[e] > ex[i2]) i2 = e;
    float inv = 1.f / (ex[i1] + ex[i2]);
    tok_i[t * 2 + 0] = i1; tok_w[t * 2 + 0] = ex[i1] * inv;
    tok_i[t * 2 + 1] = i2; tok_w[t * 2 + 1] = ex[i2] * inv;
    atomicAdd(&counts[i1], 1);
    atomicAdd(&counts[i2], 1);
  }
}

// ---------------- scan ------------------------------------------------------
__global__ void scan_kernel(const int* __restrict__ counts,
                            int* __restrict__ bases,
                            int* __restrict__ cursor) {
  if (threadIdx.x == 0) {
    int s = 0;
    for (int e = 0; e < NE; e++) { bases[e] = s; cursor[e] = s; s += counts[e]; }
    bases[NE] = s;
  }
}

// ---------------- fill ------------------------------------------------------
__global__ void fill_kernel(const int* __restrict__ tok_i,
                            const float* __restrict__ tok_w,
                            int* __restrict__ cursor,
                            int* __restrict__ slot_token,
                            float* __restrict__ slot_w,
                            int* __restrict__ slot_of) {
  int t = blockIdx.x * 256 + threadIdx.x;
  if (t >= NT) return;
#pragma unroll
  for (int k = 0; k < 2; k++) {
    int e = tok_i[t * 2 + k];
    int pos = atomicAdd(&cursor[e], 1);
    slot_token[pos] = t;
    slot_w[pos] = tok_w[t * 2 + k];
    slot_of[t * 2 + k] = pos;
  }
}

// ---------------- gather x -> bf16 xg, stored 16B-chunk-permuted ------------
// xg[slot][k]: chunk (k>>3)&7 stored at position ((k>>3)&7) ^ ((slot>>1)&7)
// within each 128B group. Makes gateup's global_load_lds a linear row copy.
__global__ void gather_kernel(const float* __restrict__ x,
                              const int* __restrict__ slot_token,
                              short* __restrict__ xg) {
  const int slot = blockIdx.x;
  const int tok = slot_token[slot];
  const int t = threadIdx.x;
  const int p = (slot >> 1) & 7;
  f32x4 v = *(const f32x4*)(x + (size_t)tok * HD + t * 4);
  short4v s;
#pragma unroll
  for (int j = 0; j < 4; j++) s[j] = f2bf(v[j]);
  *(short4v*)&xg[(size_t)slot * HD + (t >> 4) * 64 +
                 ((((t >> 1) & 7) ^ p) << 3) + ((t & 1) << 2)] = s;
}

// ---------------- gate+up grouped GEMM (BM=320 BN=64 BK=64) -----------------
// grid: (FD/64, 4, NE), block 512 (8 waves, 4m x 2n, wave tile 80x32 x2 mats)
__global__ __launch_bounds__(512, 2) void gateup_kernel(
    const short* __restrict__ xg, const float* __restrict__ gate_w,
    const float* __restrict__ up_w, const int* __restrict__ bases,
    short* __restrict__ m_out) {
  const int e = blockIdx.z;
  const int b0 = bases[e];
  const int ne = bases[e + 1] - b0;
  const int row0 = blockIdx.y * BMG;
  if (row0 >= ne) return;
  const int n0 = blockIdx.x * 64;
  const int CB = b0 + row0;

  __shared__ short As[2][BMG * 64];
  __shared__ short Bs[2][2][64 * 64];

  const int tid = threadIdx.x;
  const int lane = tid & 63, wid = tid >> 6;

  // A staging: 2560 16B-chunks, 5 per thread, linear LDS dest (glds16)
  const short* asrc[5];
#pragma unroll
  for (int j = 0; j < 5; j++) {
    int i = j * 512 + tid;
    int row = i >> 3, c = i & 7;
    int slot = b0 + imin(row0 + row, ne - 1);
    asrc[j] = xg + (size_t)slot * HD + c * 8;
  }

  // B staging: mat = tid>>8; fq fast (coalesced 256B global runs)
  const int mat = tid >> 8;
  const int r = tid & 255;
  const int fq = r & 15, kq = r >> 4;
  const float* wsel = (mat ? up_w : gate_w) + (size_t)e * HD * FD + n0 + fq * 4;

  const int wm = wid >> 1, wn = wid & 1;
  const int l15 = lane & 15, l4 = lane >> 4;

  f32x4 accG[5][2], accU[5][2];
#pragma unroll
  for (int mi = 0; mi < 5; mi++)
#pragma unroll
    for (int ni = 0; ni < 2; ni++) { accG[mi][ni] = (f32x4)0.f; accU[mi][ni] = (f32x4)0.f; }

  f32x4 bv[4];

  auto stageA = [&](int buf, int k0) {
#pragma unroll
    for (int j = 0; j < 5; j++)
      glds16(asrc[j] + k0, &As[buf][(j * 512 + wid * 64) * 8]);
  };
  auto loadB = [&](int k0) {
#pragma unroll
    for (int kk = 0; kk < 4; kk++)
      bv[kk] = *(const f32x4*)(wsel + (size_t)(k0 + kq * 4 + kk) * FD);
  };
  auto writeB = [&](int buf) {
    short* Bd = &Bs[buf][mat][0];
#pragma unroll
    for (int ff = 0; ff < 4; ff++) {
      int n = fq * 4 + ff;
      short4v wv;
#pragma unroll
      for (int kk = 0; kk < 4; kk++) wv[kk] = f2bf(bv[kk][ff]);
      *(short4v*)&Bd[n * 64 + (((kq >> 1) ^ ((n >> 1) & 7)) << 3) +
                     ((kq & 1) << 2)] = wv;
    }
  };

  const int NTL = HD / 64;   // 16
  stageA(0, 0); loadB(0); writeB(0);
  stageA(1, 64); loadB(64);
  __syncthreads();

  for (int t = 0; t < NTL; t++) {
    const int cur = t & 1;
#pragma unroll
    for (int kk = 0; kk < 2; kk++) {
      short8 a[5], bg[2], bu[2];
#pragma unroll
      for (int mi = 0; mi < 5; mi++) {
        int R = wm * 80 + mi * 16 + l15;
        int sw = ((kk * 4 + l4) ^ (((CB + R) >> 1) & 7)) << 3;
        a[mi] = *(const short8*)&As[cur][R * 64 + sw];
      }
#pragma unroll
      for (int ni = 0; ni < 2; ni++) {
        int n = wn * 32 + ni * 16 + l15;
        int sw = ((kk * 4 + l4) ^ ((n >> 1) & 7)) << 3;
        bg[ni] = *(const short8*)&Bs[cur][0][n * 64 + sw];
        bu[ni] = *(const short8*)&Bs[cur][1][n * 64 + sw];
      }
#pragma unroll
      for (int mi = 0; mi < 5; mi++)
#pragma unroll
        for (int ni = 0; ni < 2; ni++) {
          accG[mi][ni] = __builtin_amdgcn_mfma_f32_16x16x32_bf16(a[mi], bg[ni], accG[mi][ni], 0, 0, 0);
          accU[mi][ni] = __builtin_amdgcn_mfma_f32_16x16x32_bf16(a[mi], bu[ni], accU[mi][ni], 0, 0, 0);
        }
    }
    if (t + 1 < NTL) writeB(cur ^ 1);
    __syncthreads();
    if (t + 2 < NTL) { stageA(cur, (t + 2) * 64); loadB((t + 2) * 64); }
  }

  // epilogue: silu(g)*u -> bf16 m_out, stored chunk-permuted for down's glds
#pragma unroll
  for (int mi = 0; mi < 5; mi++)
#pragma unroll
    for (int ni = 0; ni < 2; ni++)
#pragma unroll
      for (int rr = 0; rr < 4; rr++) {
        int row = row0 + wm * 80 + mi * 16 + l4 * 4 + rr;
        if (row < ne) {
          int slot = b0 + row;
          float g = accG[mi][ni][rr];
          float u = accU[mi][ni][rr];
          float mv = (g / (1.f + __expf(-g))) * u;
          int psl = (slot >> 1) & 7;
          int cidx = (wn * 4 + ni * 2 + (l15 >> 3)) ^ psl;
          m_out[(size_t)slot * FD + n0 + (cidx << 3) + (l15 & 7)] = f2bf(mv);
        }
      }
}

// ---------------- down grouped GEMM (BM=320 BN=64 BK=64) --------------------
// grid: (HD/64, 4, NE), block 512
__global__ __launch_bounds__(512, 2) void down_kernel(
    const short* __restrict__ m_in, const float* __restrict__ down_w,
    const int* __restrict__ bases, const float* __restrict__ slot_w,
    float* __restrict__ out_slot) {
  const int e = blockIdx.z;
  const int b0 = bases[e];
  const int ne = bases[e + 1] - b0;
  const int row0 = blockIdx.y * BMG;
  if (row0 >= ne) return;
  const int n0 = blockIdx.x * 64;
  const int CB = b0 + row0;

  __shared__ short As[2][BMG * 64];
  __shared__ short Bs[2][64 * 64];

  const int tid = threadIdx.x;
  const int lane = tid & 63, wid = tid >> 6;

  const short* asrc[5];
#pragma unroll
  for (int j = 0; j < 5; j++) {
    int i = j * 512 + tid;
    int row = i >> 3, c = i & 7;
    int slot = b0 + imin(row0 + row, ne - 1);
    asrc[j] = m_in + (size_t)slot * FD + c * 8;
  }

  const int fq = tid & 15, kq = (tid >> 4) & 15;   // B: tid<256 only
  const float* wb = down_w + (size_t)e * FD * HD + n0 + fq * 4;

  const int wm = wid >> 1, wn = wid & 1;
  const int l15 = lane & 15, l4 = lane >> 4;

  f32x4 acc[5][2];
#pragma unroll
  for (int mi = 0; mi < 5; mi++)
#pragma unroll
    for (int ni = 0; ni < 2; ni++) acc[mi][ni] = (f32x4)0.f;

  f32x4 bv[4];

  auto stageA = [&](int buf, int k0) {
#pragma unroll
    for (int j = 0; j < 5; j++)
      glds16(asrc[j] + k0, &As[buf][(j * 512 + wid * 64) * 8]);
  };
  auto loadB = [&](int k0) {
    if (tid < 256) {
#pragma unroll
      for (int kk = 0; kk < 4; kk++)
        bv[kk] = *(const f32x4*)(wb + (size_t)(k0 + kq * 4 + kk) * HD);
    }
  };
  auto writeB = [&](int buf) {
    if (tid < 256) {
#pragma unroll
      for (int ff = 0; ff < 4; ff++) {
        int n = fq * 4 + ff;
        short4v wv;
#pragma unroll
        for (int kk = 0; kk < 4; kk++) wv[kk] = f2bf(bv[kk][ff]);
        *(short4v*)&Bs[buf][n * 64 + (((kq >> 1) ^ ((n >> 1) & 7)) << 3) +
                            ((kq & 1) << 2)] = wv;
      }
    }
  };

  const int NTL = FD / 64;   // 44
  stageA(0, 0); loadB(0); writeB(0);
  stageA(1, 64); loadB(64);
  __syncthreads();

  for (int t = 0; t < NTL; t++) {
    const int cur = t & 1;
#pragma unroll
    for (int kk = 0; kk < 2; kk++) {
      short8 a[5], bf[2];
#pragma unroll
      for (int mi = 0; mi < 5; mi++) {
        int R = wm * 80 + mi * 16 + l15;
        int sw = ((kk * 4 + l4) ^ (((CB + R) >> 1) & 7)) << 3;
        a[mi] = *(const short8*)&As[cur][R * 64 + sw];
      }
#pragma unroll
      for (int ni = 0; ni < 2; ni++) {
        int n = wn * 32 + ni * 16 + l15;
        int sw = ((kk * 4 + l4) ^ ((n >> 1) & 7)) << 3;
        bf[ni] = *(const short8*)&Bs[cur][n * 64 + sw];
      }
#pragma unroll
      for (int mi = 0; mi < 5; mi++)
#pragma unroll
        for (int ni = 0; ni < 2; ni++)
          acc[mi][ni] = __builtin_amdgcn_mfma_f32_16x16x32_bf16(a[mi], bf[ni], acc[mi][ni], 0, 0, 0);
    }
    if (t + 1 < NTL) writeB(cur ^ 1);
    __syncthreads();
    if (t + 2 < NTL) { stageA(cur, (t + 2) * 64); loadB((t + 2) * 64); }
  }

#pragma unroll
  for (int mi = 0; mi < 5; mi++)
#pragma unroll
    for (int ni = 0; ni < 2; ni++)
#pragma unroll
      for (int rr = 0; rr < 4; rr++) {
        int row = row0 + wm * 80 + mi * 16 + l4 * 4 + rr;
        if (row < ne) {
          int slot = b0 + row;
          out_slot[(size_t)slot * HD + n0 + wn * 32 + ni * 16 + l15] =
              acc[mi][ni][rr] * slot_w[slot];
        }
      }
}

// ---------------- combine ---------------------------------------------------
__global__ void combine_kernel(const float* __restrict__ out_slot,
                               const int* __restrict__ slot_of,
                               float* __restrict__ out) {
  const int t = blockIdx.x;
  const int s0 = slot_of[t * 2];
  const int s1 = slot_of[t * 2 + 1];
  const int i = threadIdx.x * 4;
  f32x4 a = *(const f32x4*)(out_slot + (size_t)s0 * HD + i);
  f32x4 b = *(const f32x4*)(out_slot + (size_t)s1 * HD + i);
  f32x4 c = a + b;
  *(f32x4*)(out + (size_t)t * HD + i) = c;
}

extern "C" void kernel_launch(void* const* d_in, const int* in_sizes, int n_in,
                              void* d_out, int out_size, void* d_ws,
                              size_t ws_size, hipStream_t stream) {
  const float* x = (const float*)d_in[0];
  const float* rw = (const float*)d_in[1];
  const float* gw = (const float*)d_in[2];
  const float* uw = (const float*)d_in[3];
  const float* dw = (const float*)d_in[4];
  float* out = (float*)d_out;

  char* ws = (char*)d_ws;
  int* counts = (int*)(ws + 0);
  int* cursor = (int*)(ws + 64);
  int* bases = (int*)(ws + 128);
  int* tok_i = (int*)(ws + 256);
  float* tok_w = (float*)(ws + 8448);
  int* slot_token = (int*)(ws + 16640);
  float* slot_w = (float*)(ws + 24832);
  int* slot_of = (int*)(ws + 33024);
  short* xg = (short*)(ws + 41216);               // 2048 x 1024 bf16 (permuted)
  short* m_buf = (short*)(ws + 4235520);          // 2048 x 2816 bf16 (permuted)
  float* out_slot = (float*)(ws + 15769856);      // 2048 x 1024 f32

  hipMemsetAsync(counts, 0, 64, stream);
  router_kernel<<<NT, 64, 0, stream>>>(x, rw, counts, tok_i, tok_w);
  scan_kernel<<<1, 64, 0, stream>>>(counts, bases, cursor);
  fill_kernel<<<NT / 256, 256, 0, stream>>>(tok_i, tok_w, cursor, slot_token,
                                            slot_w, slot_of);
  gather_kernel<<<NSLOT, 256, 0, stream>>>(x, slot_token, xg);
  gateup_kernel<<<dim3(FD / 64, 4, NE), 512, 0, stream>>>(xg, gw, uw, bases,
                                                          m_buf);
  down_kernel<<<dim3(HD / 64, 4, NE), 512, 0, stream>>>(m_buf, dw, bases,
                                                        slot_w, out_slot);
  combine_kernel<<<NT, 256, 0, stream>>>(out_slot, slot_of, out);
}